// Round 1
// baseline (286.255 us; speedup 1.0000x reference)
//
#include <hip/hip_runtime.h>
#include <math.h>

#define BS 4096
#define D 128
#define NC 512
#define MARGINF 0.1f
#define NEGV -1e30f

// ordering: higher value first; tie -> lower index (low 16 bits of key).
// Replicates jnp stable descending argsort rank exactly.
__device__ __forceinline__ bool better(float v1, int k1, float v2, int k2) {
    if (v1 != v2) return v1 > v2;
    return (k1 & 0xFFFF) < (k2 & 0xFFFF);
}

// insert (v,k) into sorted-descending 5-list. Static indexing only.
__device__ __forceinline__ void insert5(float v, int k, float (&V)[5], int (&Kk)[5]) {
    if (!better(v, k, V[4], Kk[4])) return;
    V[4] = v; Kk[4] = k;
#pragma unroll
    for (int t = 4; t > 0; --t) {
        if (better(V[t], Kk[t], V[t - 1], Kk[t - 1])) {
            float tv = V[t]; V[t] = V[t - 1]; V[t - 1] = tv;
            int tk = Kk[t]; Kk[t] = Kk[t - 1]; Kk[t - 1] = tk;
        }
    }
}

__global__ void prep_kernel(const float* __restrict__ X, const int* __restrict__ labels,
                            float* __restrict__ norms, int* __restrict__ counts) {
    int r = blockIdx.x * 256 + threadIdx.x;
    if (r >= BS) return;
    const float4* xr = (const float4*)(X + (size_t)r * D);
    float acc = 0.f;
#pragma unroll
    for (int i = 0; i < 32; ++i) {
        float4 v = xr[i];
        acc = fmaf(v.x, v.x, acc); acc = fmaf(v.y, v.y, acc);
        acc = fmaf(v.z, v.z, acc); acc = fmaf(v.w, v.w, acc);
    }
    norms[r] = acc;
    atomicAdd(&counts[labels[r]], 1);
}

// one wave per row; block = 4 waves = 4 rows; 64-col tiles staged in LDS
__global__ __launch_bounds__(256) void main_kernel(
        const float* __restrict__ X, const int* __restrict__ labels,
        const float* __restrict__ norms, const int* __restrict__ counts,
        float* __restrict__ rowres) {
    __shared__ float colbuf[64 * 132];   // 64 cols x 128 d, stride 132 (conflict-free b128)
    __shared__ float nrmS[64];
    __shared__ int   labS[64];

    const int tid  = threadIdx.x;
    const int wave = tid >> 6;
    const int lane = tid & 63;
    const int row  = blockIdx.x * 4 + wave;

    // row in registers (32 float4 = 128 VGPR)
    float4 rowv[32];
    const float4* xr = (const float4*)(X + (size_t)row * D);
#pragma unroll
    for (int i = 0; i < 32; ++i) rowv[i] = xr[i];
    const float ni    = norms[row];
    const int   myLab = labels[row];

    float gV[5]; int gK[5];   // global top-5 (key bit16 = same-class flag)
    float sV[5]; int sK[5];   // same-class top-5
#pragma unroll
    for (int t = 0; t < 5; ++t) { gV[t] = NEGV; gK[t] = 0xFFFF; sV[t] = NEGV; sK[t] = 0xFFFF; }

    for (int tile = 0; tile < 64; ++tile) {
        __syncthreads();
        // cooperative stage: 64 cols x 128 floats, coalesced global, padded LDS
        const float4* src = (const float4*)(X + (size_t)tile * 64 * D);
#pragma unroll
        for (int k2 = 0; k2 < 8; ++k2) {
            int idx = tid + k2 * 256;
            int c = idx >> 5, d4 = idx & 31;
            float4 v = src[c * 32 + d4];
            *(float4*)&colbuf[c * 132 + d4 * 4] = v;
        }
        if (tid < 64) {
            nrmS[tid] = norms[tile * 64 + tid];
            labS[tid] = labels[tile * 64 + tid];
        }
        __syncthreads();

        const int j = tile * 64 + lane;
        const float4* cb = (const float4*)&colbuf[lane * 132];
        float acc = 0.f;
#pragma unroll
        for (int i = 0; i < 32; ++i) {
            float4 c4 = cb[i]; float4 r4 = rowv[i];
            acc = fmaf(r4.x, c4.x, acc); acc = fmaf(r4.y, c4.y, acc);
            acc = fmaf(r4.z, c4.z, acc); acc = fmaf(r4.w, c4.w, acc);
        }
        float d2  = fmaxf(ni + nrmS[lane] - 2.f * acc, 0.f);
        float sim = -sqrtf(d2);
        bool same = (labS[lane] == myLab);
        float simi = same ? sim : (sim + MARGINF);
        insert5(simi, j | (same ? 0x10000 : 0), gV, gK);
        if (same) insert5(simi, j, sV, sK);
    }

    // butterfly merge across the wave (all lanes converge to the row top-5s)
#pragma unroll
    for (int off = 1; off < 64; off <<= 1) {
        float bV[5]; int bK[5];
#pragma unroll
        for (int t = 0; t < 5; ++t) { bV[t] = __shfl_xor(gV[t], off); bK[t] = __shfl_xor(gK[t], off); }
#pragma unroll
        for (int t = 0; t < 5; ++t) insert5(bV[t], bK[t], gV, gK);
#pragma unroll
        for (int t = 0; t < 5; ++t) { bV[t] = __shfl_xor(sV[t], off); bK[t] = __shfl_xor(sK[t], off); }
#pragma unroll
        for (int t = 0; t < 5; ++t) insert5(bV[t], bK[t], sV, sK);
    }

    if (lane == 0) {
        int pos = counts[myLab];
        int ks  = (pos < 5) ? pos : 5;          // min(pos_nums, K+1)
        float fpsum = 0.f; int fpn = 0;
#pragma unroll
        for (int r = 0; r < 5; ++r) {
            bool isFp = (r < ks) && !((gK[r] >> 16) & 1);
            if (isFp) { fpsum += gV[r]; fpn++; }
        }
        int s = ks - fpn;                        // same-class entries inside top-ks
        float fnsum = 0.f;
#pragma unroll
        for (int t = 0; t < 5; ++t) {
            if (t >= s && t < s + fpn) fnsum += sV[t];
        }
        rowres[row] = fpsum - fnsum;
    }
}

__global__ void reduce_kernel(const float* __restrict__ rowres, float* __restrict__ out) {
    __shared__ float sh[256];
    float acc = 0.f;
    for (int i = threadIdx.x; i < BS; i += 256) acc += rowres[i];
    sh[threadIdx.x] = acc;
    __syncthreads();
    for (int s = 128; s > 0; s >>= 1) {
        if (threadIdx.x < s) sh[threadIdx.x] += sh[threadIdx.x + s];
        __syncthreads();
    }
    if (threadIdx.x == 0) out[0] = sh[0];
}

extern "C" void kernel_launch(void* const* d_in, const int* in_sizes, int n_in,
                              void* d_out, int out_size, void* d_ws, size_t ws_size,
                              hipStream_t stream) {
    const float* X      = (const float*)d_in[0];
    const int*   labels = (const int*)d_in[1];

    float* ws     = (float*)d_ws;
    float* rowres = ws;            // 4096 f32
    float* norms  = ws + BS;       // 4096 f32
    int*   counts = (int*)(ws + 2 * BS); // 512 i32

    hipMemsetAsync(counts, 0, NC * sizeof(int), stream);
    prep_kernel<<<BS / 256, 256, 0, stream>>>(X, labels, norms, counts);
    main_kernel<<<BS / 4, 256, 0, stream>>>(X, labels, norms, counts, rowres);
    reduce_kernel<<<1, 256, 0, stream>>>(rowres, (float*)d_out);
}

// Round 2
// 248.267 us; speedup vs baseline: 1.1530x; 1.1530x over previous
//
#include <hip/hip_runtime.h>
#include <math.h>

#define BS 4096
#define D 128
#define NC 512
#define NSLICE 8
#define SLICE_COLS 512
#define PANELS 4
#define MARGINF 0.1f
#define NEGV -1e30f

typedef float f32x4 __attribute__((ext_vector_type(4)));
typedef short s16x8 __attribute__((ext_vector_type(8)));

#define ASTR 136   // ushorts per LDS row (128 + 8 pad)
#define AH_OFF 0
#define AL_OFF 34816
#define BH_OFF 69632
#define BL_OFF 104448

__device__ __forceinline__ unsigned short f2bf(float f) {
    unsigned int u = __float_as_uint(f);
    unsigned int r = u + 0x7FFFu + ((u >> 16) & 1u);
    return (unsigned short)(r >> 16);
}
__device__ __forceinline__ float bf2f(unsigned short h) {
    return __uint_as_float(((unsigned int)h) << 16);
}

// ordering: higher value first; tie -> lower index (low 16 bits of key).
__device__ __forceinline__ bool better(float v1, int k1, float v2, int k2) {
    if (v1 != v2) return v1 > v2;
    return (k1 & 0xFFFF) < (k2 & 0xFFFF);
}

__device__ __forceinline__ void insert5(float v, int k, float (&V)[5], int (&Kk)[5]) {
    if (!better(v, k, V[4], Kk[4])) return;
    V[4] = v; Kk[4] = k;
#pragma unroll
    for (int t = 4; t > 0; --t) {
        if (better(V[t], Kk[t], V[t - 1], Kk[t - 1])) {
            float tv = V[t]; V[t] = V[t - 1]; V[t - 1] = tv;
            int tk = Kk[t]; Kk[t] = Kk[t - 1]; Kk[t - 1] = tk;
        }
    }
}

// norms (coalesced, segmented shfl reduce) + class histogram
__global__ void prep_kernel(const float* __restrict__ X, const int* __restrict__ labels,
                            float* __restrict__ norms, int* __restrict__ counts) {
    int t = blockIdx.x * 256 + threadIdx.x;       // float4 index, 131072 total
    int r = t >> 5, kq = t & 31;
    float4 v = ((const float4*)X)[t];
    float acc = v.x * v.x + v.y * v.y + v.z * v.z + v.w * v.w;
#pragma unroll
    for (int off = 1; off < 32; off <<= 1) acc += __shfl_xor(acc, off);
    if (kq == 0) norms[r] = acc;
    if (t < BS) atomicAdd(&counts[labels[t]], 1);
}

__global__ __launch_bounds__(256) void main_kernel(
        const float* __restrict__ X, const int* __restrict__ labels,
        const float* __restrict__ norms, float* __restrict__ lists) {
    __shared__ __align__(16) char lds[139264];
    __shared__ float ncS[128];
    __shared__ int   lcS[128];

    unsigned short* Ah = (unsigned short*)(lds + AH_OFF);
    unsigned short* Al = (unsigned short*)(lds + AL_OFF);
    unsigned short* Bh = (unsigned short*)(lds + BH_OFF);
    unsigned short* Bl = (unsigned short*)(lds + BL_OFF);
    float* Sb = (float*)(lds + BH_OFF);   // aliases B region: [128][132] f32

    const int t = threadIdx.x;
    const int bx = blockIdx.x;
    const int rb = bx >> 3, cs = bx & 7;
    const int row0 = rb * 128;
    const int lane = t & 63, wave = t >> 6;
    const int wr = (wave >> 1) * 64, wc = (wave & 1) * 64;

    // selection identity: each thread owns one row, one col-half
    const int rsel = t >> 1, h = t & 1;
    const int rowG = row0 + rsel;
    const float nR = norms[rowG];
    const int   lR = labels[rowG];

    float gV[5]; int gK[5]; float sV[5]; int sK[5];
#pragma unroll
    for (int i = 0; i < 5; ++i) { gV[i] = NEGV; gK[i] = 0xFFFF; sV[i] = NEGV; sK[i] = 0xFFFF; }

    // ---- stage A panel (rows, hi+lo split) once ----
#pragma unroll
    for (int i = 0; i < 16; ++i) {
        int idx = i * 256 + t;
        int r = idx >> 5, kq = idx & 31;
        float4 v = *(const float4*)(X + (size_t)(row0 + r) * D + kq * 4);
        unsigned short h0 = f2bf(v.x), h1 = f2bf(v.y), h2 = f2bf(v.z), h3 = f2bf(v.w);
        ushort4 hv = {h0, h1, h2, h3};
        ushort4 lv = { f2bf(v.x - bf2f(h0)), f2bf(v.y - bf2f(h1)),
                       f2bf(v.z - bf2f(h2)), f2bf(v.w - bf2f(h3)) };
        *(ushort4*)(Ah + r * ASTR + kq * 4) = hv;
        *(ushort4*)(Al + r * ASTR + kq * 4) = lv;
    }

    for (int p = 0; p < PANELS; ++p) {
        const int col0 = cs * SLICE_COLS + p * 128;
        __syncthreads();   // prev panel's selection done (Sb/ncS reusable)

        // ---- stage B panel (cols, hi+lo split) ----
#pragma unroll
        for (int i = 0; i < 16; ++i) {
            int idx = i * 256 + t;
            int c = idx >> 5, kq = idx & 31;
            float4 v = *(const float4*)(X + (size_t)(col0 + c) * D + kq * 4);
            unsigned short h0 = f2bf(v.x), h1 = f2bf(v.y), h2 = f2bf(v.z), h3 = f2bf(v.w);
            ushort4 hv = {h0, h1, h2, h3};
            ushort4 lv = { f2bf(v.x - bf2f(h0)), f2bf(v.y - bf2f(h1)),
                           f2bf(v.z - bf2f(h2)), f2bf(v.w - bf2f(h3)) };
            *(ushort4*)(Bh + c * ASTR + kq * 4) = hv;
            *(ushort4*)(Bl + c * ASTR + kq * 4) = lv;
        }
        if (t < 128) {
            ncS[t] = norms[col0 + t];
            lcS[t] = labels[col0 + t];
        }
        __syncthreads();   // B ready (covers A for p=0)

        // ---- MFMA k-loop: S = Ah*Bh^T + Ah*Bl^T + Al*Bh^T ----
        f32x4 acc[4][4];
#pragma unroll
        for (int i = 0; i < 4; ++i)
#pragma unroll
            for (int j = 0; j < 4; ++j) acc[i][j] = (f32x4){0.f, 0.f, 0.f, 0.f};

#pragma unroll
        for (int ks = 0; ks < 4; ++ks) {
            const int ko = ks * 32 + (lane >> 4) * 8;
            s16x8 ahi[4], alo[4], bhi[4], blo[4];
#pragma unroll
            for (int i = 0; i < 4; ++i) {
                int ra = (wr + i * 16 + (lane & 15)) * ASTR + ko;
                ahi[i] = *(const s16x8*)(Ah + ra);
                alo[i] = *(const s16x8*)(Al + ra);
                int rc = (wc + i * 16 + (lane & 15)) * ASTR + ko;
                bhi[i] = *(const s16x8*)(Bh + rc);
                blo[i] = *(const s16x8*)(Bl + rc);
            }
#pragma unroll
            for (int i = 0; i < 4; ++i)
#pragma unroll
                for (int j = 0; j < 4; ++j) {
                    acc[i][j] = __builtin_amdgcn_mfma_f32_16x16x32_bf16(ahi[i], bhi[j], acc[i][j], 0, 0, 0);
                    acc[i][j] = __builtin_amdgcn_mfma_f32_16x16x32_bf16(ahi[i], blo[j], acc[i][j], 0, 0, 0);
                    acc[i][j] = __builtin_amdgcn_mfma_f32_16x16x32_bf16(alo[i], bhi[j], acc[i][j], 0, 0, 0);
                }
        }
        __syncthreads();   // all waves done reading B before overwrite

        // ---- spill S panel to LDS (C layout: col=lane&15, row=(lane>>4)*4+e) ----
#pragma unroll
        for (int i = 0; i < 4; ++i)
#pragma unroll
            for (int j = 0; j < 4; ++j)
#pragma unroll
                for (int e = 0; e < 4; ++e) {
                    int R = wr + i * 16 + (lane >> 4) * 4 + e;
                    int C = wc + j * 16 + (lane & 15);
                    Sb[R * 132 + C] = acc[i][j][e];
                }
        __syncthreads();   // S ready

        // ---- selection: row-per-thread over 64 cols ----
#pragma unroll
        for (int i4 = 0; i4 < 16; ++i4) {
            int cbase = h * 64 + i4 * 4;
            float4 s4 = *(const float4*)(Sb + rsel * 132 + cbase);
            float sv4[4] = {s4.x, s4.y, s4.z, s4.w};
#pragma unroll
            for (int e = 0; e < 4; ++e) {
                int c = cbase + e;
                int j = col0 + c;
                float d2 = fmaxf(nR + ncS[c] - 2.f * sv4[e], 0.f);
                float sim = (j == rowG) ? 0.f : -sqrtf(d2);
                bool same = (lcS[c] == lR);
                float simi = same ? sim : (sim + MARGINF);
                insert5(simi, j | (same ? 0x10000 : 0), gV, gK);
                if (same) insert5(simi, j, sV, sK);
            }
        }
    }

    // ---- merge the two col-halves (snapshot partner lists first) ----
    float bv5[5]; int bk5[5];
#pragma unroll
    for (int i = 0; i < 5; ++i) { bv5[i] = __shfl_xor(gV[i], 1); bk5[i] = __shfl_xor(gK[i], 1); }
#pragma unroll
    for (int i = 0; i < 5; ++i) insert5(bv5[i], bk5[i], gV, gK);
#pragma unroll
    for (int i = 0; i < 5; ++i) { bv5[i] = __shfl_xor(sV[i], 1); bk5[i] = __shfl_xor(sK[i], 1); }
#pragma unroll
    for (int i = 0; i < 5; ++i) insert5(bv5[i], bk5[i], sV, sK);

    if (h == 0) {
        float* Lp = lists + (size_t)(rowG * NSLICE + cs) * 20;
        int* Li = (int*)Lp;
#pragma unroll
        for (int i = 0; i < 5; ++i) {
            Lp[i] = gV[i]; Li[5 + i] = gK[i];
            Lp[10 + i] = sV[i]; Li[15 + i] = sK[i];
        }
    }
}

__global__ void merge_kernel(const float* __restrict__ lists, const int* __restrict__ counts,
                             const int* __restrict__ labels, float* __restrict__ rowres) {
    int r = blockIdx.x * 256 + threadIdx.x;
    if (r >= BS) return;
    float gV[5]; int gK[5]; float sV[5]; int sK[5];
#pragma unroll
    for (int i = 0; i < 5; ++i) { gV[i] = NEGV; gK[i] = 0xFFFF; sV[i] = NEGV; sK[i] = 0xFFFF; }
    for (int s2 = 0; s2 < NSLICE; ++s2) {
        const float* Lp = lists + (size_t)(r * NSLICE + s2) * 20;
        const int* Li = (const int*)Lp;
#pragma unroll
        for (int i = 0; i < 5; ++i) insert5(Lp[i], Li[5 + i], gV, gK);
#pragma unroll
        for (int i = 0; i < 5; ++i) insert5(Lp[10 + i], Li[15 + i], sV, sK);
    }
    int pos = counts[labels[r]];
    int ks = (pos < 5) ? pos : 5;
    float fpsum = 0.f; int fpn = 0;
#pragma unroll
    for (int i = 0; i < 5; ++i) {
        bool isFp = (i < ks) && !((gK[i] >> 16) & 1);
        if (isFp) { fpsum += gV[i]; fpn++; }
    }
    int s0 = ks - fpn;
    float fnsum = 0.f;
#pragma unroll
    for (int i = 0; i < 5; ++i)
        if (i >= s0 && i < s0 + fpn) fnsum += sV[i];
    rowres[r] = fpsum - fnsum;
}

__global__ void reduce_kernel(const float* __restrict__ rowres, float* __restrict__ out) {
    __shared__ float sh[256];
    float acc = 0.f;
    for (int i = threadIdx.x; i < BS; i += 256) acc += rowres[i];
    sh[threadIdx.x] = acc;
    __syncthreads();
    for (int s = 128; s > 0; s >>= 1) {
        if (threadIdx.x < s) sh[threadIdx.x] += sh[threadIdx.x + s];
        __syncthreads();
    }
    if (threadIdx.x == 0) out[0] = sh[0];
}

extern "C" void kernel_launch(void* const* d_in, const int* in_sizes, int n_in,
                              void* d_out, int out_size, void* d_ws, size_t ws_size,
                              hipStream_t stream) {
    const float* X      = (const float*)d_in[0];
    const int*   labels = (const int*)d_in[1];

    float* ws     = (float*)d_ws;
    float* norms  = ws;                 // 4096 f32
    float* rowres = ws + BS;            // 4096 f32
    int*   counts = (int*)(ws + 2 * BS);// 512 i32
    float* lists  = ws + 2 * BS + 512;  // 4096*8*20 f32 = 2.62 MB

    hipMemsetAsync(counts, 0, NC * sizeof(int), stream);
    prep_kernel<<<(BS * D / 4) / 256, 256, 0, stream>>>(X, labels, norms, counts);
    main_kernel<<<32 * NSLICE, 256, 0, stream>>>(X, labels, norms, lists);
    merge_kernel<<<BS / 256, 256, 0, stream>>>(lists, counts, labels, rowres);
    reduce_kernel<<<1, 256, 0, stream>>>(rowres, (float*)d_out);
}